// Round 10
// baseline (1582.768 us; speedup 1.0000x reference)
//
#include <hip/hip_runtime.h>
#include <cstdint>
#include <cstddef>

#define M_ROWS 32768   // B*T
#define K_CODES 8192
#define H_DIM 512
#define TAU 2.5e-4f
#define MAXFLAG 32768

typedef float  f32x4  __attribute__((ext_vector_type(4)));
typedef float  f32x16 __attribute__((ext_vector_type(16)));
typedef short  s16x8  __attribute__((ext_vector_type(8)));

typedef __attribute__((address_space(3))) void as3_void;
typedef const __attribute__((address_space(1))) void as1_cvoid;
#define GLD16(gp, lp) __builtin_amdgcn_global_load_lds((as1_cvoid*)(gp), (as3_void*)(lp), 16, 0, 0)
#define SB0() __builtin_amdgcn_sched_barrier(0)

// ---------------------------------------------------------------------------
// bf16 split helpers (RNE)
// ---------------------------------------------------------------------------
__device__ __forceinline__ unsigned short f2bf(float f) {
    uint32_t u = __float_as_uint(f);
    u = u + 0x7fffu + ((u >> 16) & 1u);
    return (unsigned short)(u >> 16);
}
__device__ __forceinline__ float bf2f(unsigned short h) {
    return __uint_as_float(((uint32_t)h) << 16);
}

__global__ __launch_bounds__(256) void split_all_kernel(
    const float* __restrict__ z, const float* __restrict__ emb,
    unsigned short* __restrict__ zh, unsigned short* __restrict__ zl,
    unsigned short* __restrict__ eh, unsigned short* __restrict__ el)
{
    const int ZQ = M_ROWS * H_DIM / 4;
    const int EQ = K_CODES * H_DIM / 4;
    int t = blockIdx.x * 256 + threadIdx.x;
    const float* src; unsigned short* hi; unsigned short* lo;
    if (t < ZQ)           { src = z;   hi = zh; lo = zl; }
    else if (t < ZQ + EQ) { t -= ZQ; src = emb; hi = eh; lo = el; }
    else return;
    const float4 v = reinterpret_cast<const float4*>(src)[t];
    ushort4 h, l;
    h.x = f2bf(v.x); l.x = f2bf(v.x - bf2f(h.x));
    h.y = f2bf(v.y); l.y = f2bf(v.y - bf2f(h.y));
    h.z = f2bf(v.z); l.z = f2bf(v.z - bf2f(h.z));
    h.w = f2bf(v.w); l.w = f2bf(v.w - bf2f(h.w));
    reinterpret_cast<ushort4*>(hi)[t] = h;
    reinterpret_cast<ushort4*>(lo)[t] = l;
}

// ---------------------------------------------------------------------------
// numpy pairwise sum-of-squares (bit-exact), 32 lanes per row
// ---------------------------------------------------------------------------
__device__ __forceinline__ float np_sumsq_row32(const float* __restrict__ row,
                                                int lane32) {
    const int c = lane32 >> 3, j = lane32 & 7;
    const float* p = row + c * 128 + j;
    float s = __fmul_rn(p[0], p[0]);
    #pragma unroll
    for (int t = 1; t < 16; ++t) {
        const float v = p[8 * t];
        s = __fadd_rn(s, __fmul_rn(v, v));
    }
    s = __fadd_rn(s, __shfl_xor(s, 1));
    s = __fadd_rn(s, __shfl_xor(s, 2));
    s = __fadd_rn(s, __shfl_xor(s, 4));
    s = __fadd_rn(s, __shfl_xor(s, 8));
    s = __fadd_rn(s, __shfl_xor(s, 16));
    return s;
}

__global__ __launch_bounds__(256) void rowsq_all_kernel(
    const float* __restrict__ z, const float* __restrict__ emb,
    float* __restrict__ x2, float* __restrict__ e2,
    float* __restrict__ loss_slots, int* __restrict__ flag_count)
{
    const int slot = blockIdx.x * 8 + (threadIdx.x >> 5);
    if (slot < M_ROWS) {
        const float s = np_sumsq_row32(z + (size_t)slot * H_DIM, threadIdx.x & 31);
        if ((threadIdx.x & 31) == 0) x2[slot] = s;
    } else if (slot < M_ROWS + K_CODES) {
        const int r = slot - M_ROWS;
        const float s = np_sumsq_row32(emb + (size_t)r * H_DIM, threadIdx.x & 31);
        if ((threadIdx.x & 31) == 0) e2[r] = s;
    }
    if (blockIdx.x == 0) {
        if (threadIdx.x < 2) loss_slots[threadIdx.x] = 0.f;
        if (threadIdx.x == 0) *flag_count = 0;
    }
}

// ---------------------------------------------------------------------------
// top-2 merge helper (tie -> lower index)
// ---------------------------------------------------------------------------
__device__ __forceinline__ void top2_merge(float& b1, int& ix, float& b2,
                                           float ob1, int oix, float ob2) {
    if (ob1 < b1)      { b2 = fminf(b1, ob2); b1 = ob1; ix = oix; }
    else if (ob1 > b1) { b2 = fminf(b2, ob1); }
    else               { if (oix < ix) ix = oix; b2 = b1; }
}

// ---------------------------------------------------------------------------
// MFMA distance GEMM + top-2 argmin. 256x256, 8 waves, BK=32, 16 K-steps,
// dbuf 128 KB, counted vmcnt(8) + raw barriers (r6-r9 verified).
// NEW r10: v_mfma_f32_32x32x16_bf16 (half the MFMA insts, +15% pipe rate)
// + counted lgkmcnt(8) so kk0 MFMAs overlap kk1 ds_reads in flight.
// A-frag: row=l&31, k-half=l>>5; C/D: col=lane&31, row=(reg&3)+8(reg>>2)+4(l>>5).
// ---------------------------------------------------------------------------
__global__ __launch_bounds__(512, 1) void mfma_dist_kernel(
    const unsigned short* __restrict__ zh, const unsigned short* __restrict__ zl,
    const unsigned short* __restrict__ eh, const unsigned short* __restrict__ el,
    const float* __restrict__ x2, const float* __restrict__ e2,
    float* __restrict__ pb1, float* __restrict__ pb2, int* __restrict__ pidx)
{
    __shared__ __align__(16) unsigned short lb[2][4][8192];   // 128 KiB

    const int tid = threadIdx.x;
    const int l   = tid & 63;
    const int w   = tid >> 6;          // 0..7
    const int wm  = w >> 2;            // 0..1  (row half: 128 rows)
    const int wn  = w & 3;             // 0..3  (code quarter: 64 codes)

    // XCD-banded block swizzle
    const int bid  = blockIdx.x;
    const int xcd  = bid & 7;
    const int sq   = bid >> 3;
    const int band = sq >> 7;
    const int r128 = sq & 127;
    const int ct   = r128 >> 2;
    const int rt   = (band * 8 + xcd) * 4 + (r128 & 3);
    const int row0 = rt * 256;
    const int c0   = ct * 256;

    // staging: wave w stages matrix m = w>>1, row-half = w&1 (unchanged layout)
    const int m    = w >> 1;           // 0=Ah 1=Al 2=Bh 3=Bl
    const int half = w & 1;
    const unsigned short* sp = (m == 0) ? zh : (m == 1) ? zl : (m == 2) ? eh : el;
    const int rbase0 = (m < 2) ? row0 : c0;
    const unsigned short* sb = sp
        + (size_t)(rbase0 + half * 128 + (l >> 2)) * H_DIM
        + ((l & 3) ^ ((l >> 3) & 3)) * 8;

    // ds_read geometry for 32x32 frags (swizzled: slot = chunk ^ ((row>>1)&3))
    const int ar    = l & 31;             // row within 32-row frag
    const int hsel  = l >> 5;             // k-half select
    const int axr   = (ar >> 1) & 3;
    const int soff0 = (((0 << 1) + hsel) ^ axr) * 16;   // kk=0 slot bytes
    const int soff1 = (((1 << 1) + hsel) ^ axr) * 16;   // kk=1 slot bytes
    const int abase = (wm * 128 + ar) * 64;
    const int bbase = (wn * 64  + ar) * 64;

    f32x16 acc[4][2];
    #pragma unroll
    for (int i = 0; i < 4; ++i)
        #pragma unroll
        for (int j = 0; j < 2; ++j)
            #pragma unroll
            for (int r = 0; r < 16; ++r) acc[i][j][r] = 0.f;

    // prologue: stage step 0 into parity 0
    {
        char* dst = (char*)&lb[0][m][0] + half * 8192;
        #pragma unroll
        for (int t = 0; t < 8; ++t)
            GLD16(sb + (size_t)t * 16 * H_DIM, dst + t * 1024);
    }
    asm volatile("s_waitcnt vmcnt(0)" ::: "memory");
    __builtin_amdgcn_s_barrier();

    for (int s = 0; s < 16; ++s) {
        const int par = s & 1;

        if (s < 15) {
            const unsigned short* src = sb + (s + 1) * 32;
            char* dst = (char*)&lb[par ^ 1][m][0] + half * 8192;
            #pragma unroll
            for (int t = 0; t < 8; ++t)
                GLD16(src + (size_t)t * 16 * H_DIM, dst + t * 1024);
            asm volatile("s_waitcnt vmcnt(8)" ::: "memory");   // oldest 8 = this step
        } else {
            asm volatile("s_waitcnt vmcnt(0)" ::: "memory");
        }
        __builtin_amdgcn_s_barrier();

        const char* pAh = (const char*)&lb[par][0][0];
        const char* pAl = (const char*)&lb[par][1][0];
        const char* pBh = (const char*)&lb[par][2][0];
        const char* pBl = (const char*)&lb[par][3][0];

        // --- issue kk0 frags (12) then kk1 A-frags (8): 20 reads outstanding
        s16x8 ah0[4], av0[4], bh0[2], bv0[2];
        #pragma unroll
        for (int i = 0; i < 4; ++i) {
            ah0[i] = *(const s16x8*)(pAh + abase + i * 2048 + soff0);
            av0[i] = *(const s16x8*)(pAl + abase + i * 2048 + soff0);
        }
        #pragma unroll
        for (int j = 0; j < 2; ++j) {
            bh0[j] = *(const s16x8*)(pBh + bbase + j * 2048 + soff0);
            bv0[j] = *(const s16x8*)(pBl + bbase + j * 2048 + soff0);
        }
        SB0();
        s16x8 ah1[4], av1[4];
        #pragma unroll
        for (int i = 0; i < 4; ++i) {
            ah1[i] = *(const s16x8*)(pAh + abase + i * 2048 + soff1);
            av1[i] = *(const s16x8*)(pAl + abase + i * 2048 + soff1);
        }
        SB0();
        asm volatile("s_waitcnt lgkmcnt(8)" ::: "memory");   // kk0's 12 complete
        SB0();

        __builtin_amdgcn_s_setprio(1);
        // kk0 G1: ah0 x bv0 (8 indep)
        #pragma unroll
        for (int j = 0; j < 2; ++j)
            #pragma unroll
            for (int i = 0; i < 4; ++i)
                acc[i][j] = __builtin_amdgcn_mfma_f32_32x32x16_bf16(ah0[i], bv0[j], acc[i][j], 0, 0, 0);
        // kk0 G2: ah0 x bh0
        #pragma unroll
        for (int j = 0; j < 2; ++j)
            #pragma unroll
            for (int i = 0; i < 4; ++i)
                acc[i][j] = __builtin_amdgcn_mfma_f32_32x32x16_bf16(ah0[i], bh0[j], acc[i][j], 0, 0, 0);
        __builtin_amdgcn_s_setprio(0);
        SB0();
        // issue kk1 B-frags (4) — overlap with G3 below
        s16x8 bh1[2], bv1[2];
        #pragma unroll
        for (int j = 0; j < 2; ++j) {
            bh1[j] = *(const s16x8*)(pBh + bbase + j * 2048 + soff1);
            bv1[j] = *(const s16x8*)(pBl + bbase + j * 2048 + soff1);
        }
        SB0();
        __builtin_amdgcn_s_setprio(1);
        // kk0 G3: av0 x bh0
        #pragma unroll
        for (int j = 0; j < 2; ++j)
            #pragma unroll
            for (int i = 0; i < 4; ++i)
                acc[i][j] = __builtin_amdgcn_mfma_f32_32x32x16_bf16(av0[i], bh0[j], acc[i][j], 0, 0, 0);
        __builtin_amdgcn_s_setprio(0);
        asm volatile("s_waitcnt lgkmcnt(0)" ::: "memory");
        SB0();
        __builtin_amdgcn_s_setprio(1);
        // kk1 G1/G2/G3
        #pragma unroll
        for (int j = 0; j < 2; ++j)
            #pragma unroll
            for (int i = 0; i < 4; ++i)
                acc[i][j] = __builtin_amdgcn_mfma_f32_32x32x16_bf16(ah1[i], bv1[j], acc[i][j], 0, 0, 0);
        #pragma unroll
        for (int j = 0; j < 2; ++j)
            #pragma unroll
            for (int i = 0; i < 4; ++i)
                acc[i][j] = __builtin_amdgcn_mfma_f32_32x32x16_bf16(ah1[i], bh1[j], acc[i][j], 0, 0, 0);
        #pragma unroll
        for (int j = 0; j < 2; ++j)
            #pragma unroll
            for (int i = 0; i < 4; ++i)
                acc[i][j] = __builtin_amdgcn_mfma_f32_32x32x16_bf16(av1[i], bh1[j], acc[i][j], 0, 0, 0);
        __builtin_amdgcn_s_setprio(0);

        __builtin_amdgcn_s_barrier();   // all reads of par done -> next GLD safe
    }

    // --- fold: np-order d, top-2 per row across j and 32 lanes, LDS merge ---
    float* mb1 = (float*)&lb[0][0][0];   // [4][256]
    float* mb2 = mb1 + 1024;
    int*   mi  = (int*)(mb1 + 2048);

    float e2v[2];
    #pragma unroll
    for (int j = 0; j < 2; ++j)
        e2v[j] = e2[c0 + wn * 64 + j * 32 + ar];
    const int colb = c0 + wn * 64 + ar;   // column this lane owns (j adds 32)

    #pragma unroll
    for (int i = 0; i < 4; ++i) {
        #pragma unroll
        for (int g = 0; g < 4; ++g) {
            const float4 x2v = *reinterpret_cast<const float4*>(
                x2 + row0 + wm * 128 + i * 32 + g * 8 + 4 * hsel);
            const float x2a[4] = {x2v.x, x2v.y, x2v.z, x2v.w};
            #pragma unroll
            for (int r2 = 0; r2 < 4; ++r2) {
                const int reg = g * 4 + r2;
                float b1 = 3.4e38f, b2 = 3.4e38f; int ix = 0;
                #pragma unroll
                for (int j = 0; j < 2; ++j) {
                    const float d = __fadd_rn(__fmaf_rn(-2.f, acc[i][j][reg], x2a[r2]), e2v[j]);
                    const int cj = colb + j * 32;
                    if (d < b1)      { b2 = b1; b1 = d; ix = cj; }
                    else if (d < b2) { b2 = d; }
                }
                #pragma unroll
                for (int mm = 1; mm <= 16; mm <<= 1) {
                    const float ob1 = __shfl_xor(b1, mm);
                    const float ob2 = __shfl_xor(b2, mm);
                    const int   oix = __shfl_xor(ix, mm);
                    top2_merge(b1, ix, b2, ob1, oix, ob2);
                }
                if (ar == 0) {
                    const int rl = wm * 128 + i * 32 + r2 + 8 * g + 4 * hsel;
                    mb1[wn * 256 + rl] = b1;
                    mb2[wn * 256 + rl] = b2;
                    mi [wn * 256 + rl] = ix;
                }
            }
        }
    }
    __syncthreads();
    if (tid < 256) {
        float b1 = mb1[tid], b2 = mb2[tid]; int ix = mi[tid];
        #pragma unroll
        for (int q = 1; q < 4; ++q)
            top2_merge(b1, ix, b2, mb1[q * 256 + tid], mi[q * 256 + tid], mb2[q * 256 + tid]);
        const size_t o = (size_t)ct * M_ROWS + row0 + tid;
        pb1[o] = b1; pb2[o] = b2; pidx[o] = ix;
    }
}

// merge the 32 code-split partials per row; emit idx + ambiguity flags
__global__ __launch_bounds__(256) void combine_kernel(
    const float* __restrict__ pb1, const float* __restrict__ pb2,
    const int* __restrict__ pidx,
    int* __restrict__ idx_i, float* __restrict__ idx_f,
    int* __restrict__ flag_count, int* __restrict__ flag_rows)
{
    const int r = blockIdx.x * 256 + threadIdx.x;
    if (r >= M_ROWS) return;
    float b1 = pb1[r], b2 = pb2[r]; int ix = pidx[r];
    #pragma unroll 4
    for (int ct = 1; ct < 32; ++ct)
        top2_merge(b1, ix, b2, pb1[(size_t)ct * M_ROWS + r],
                   pidx[(size_t)ct * M_ROWS + r], pb2[(size_t)ct * M_ROWS + r]);
    idx_i[r] = ix;
    idx_f[r] = (float)ix;
    if (b2 - b1 < TAU) {
        const int p = atomicAdd(flag_count, 1);
        if (p < MAXFLAG) flag_rows[p] = r;
    }
}

// ---------------------------------------------------------------------------
// FALLBACK (round-3 fp32 path) — only if ws_size too small
// ---------------------------------------------------------------------------
#define BM 64
#define BN 128
#define BH 32
#define PADZ 4
#define PADE 4

__device__ __forceinline__ void stage_transposed(const float* __restrict__ src,
                                                 int row0, int h0,
                                                 float* lds, int R, int ldp) {
    const int nf4 = R * (BH / 4);
    for (int f = threadIdx.x; f < nf4; f += 256) {
        const int r  = f / (BH / 4);
        const int c4 = (f % (BH / 4)) * 4;
        const float4 v = *reinterpret_cast<const float4*>(
            src + (size_t)(row0 + r) * H_DIM + h0 + c4);
        lds[(c4 + 0) * ldp + r] = v.x;
        lds[(c4 + 1) * ldp + r] = v.y;
        lds[(c4 + 2) * ldp + r] = v.z;
        lds[(c4 + 3) * ldp + r] = v.w;
    }
}

__global__ __launch_bounds__(256) void dist_argmin_kernel(
    const float* __restrict__ z, const float* __restrict__ emb,
    const float* __restrict__ x2, const float* __restrict__ e2,
    int* __restrict__ idx_i, float* __restrict__ idx_f,
    int* __restrict__ flag_count, int* __restrict__ flag_rows)
{
    __shared__ float zs[BH * (BM + PADZ)];
    __shared__ float es[BH * (BN + PADE)];
    __shared__ float bd[BM][17];
    __shared__ float bd2[BM][17];
    __shared__ int   bi[BM][17];

    const int row0 = blockIdx.x * BM;
    const int tx = threadIdx.x & 15;
    const int ty = threadIdx.x >> 4;

    float x2r[4];
    #pragma unroll
    for (int i = 0; i < 4; ++i) x2r[i] = x2[row0 + ty * 4 + i];

    float best[4], best2[4];
    int   bidx[4];
    #pragma unroll
    for (int i = 0; i < 4; ++i) { best[i] = 3.4e38f; best2[i] = 3.4e38f; bidx[i] = 0; }

    for (int nt = 0; nt < K_CODES / BN; ++nt) {
        float acc[4][8];
        #pragma unroll
        for (int i = 0; i < 4; ++i)
            #pragma unroll
            for (int j = 0; j < 8; ++j) acc[i][j] = 0.f;

        for (int hc = 0; hc < H_DIM / BH; ++hc) {
            __syncthreads();
            stage_transposed(z,   row0,    hc * BH, zs, BM, BM + PADZ);
            stage_transposed(emb, nt * BN, hc * BH, es, BN, BN + PADE);
            __syncthreads();
            #pragma unroll
            for (int h = 0; h < BH; ++h) {
                const float4 zr = *reinterpret_cast<const float4*>(&zs[h * (BM + PADZ) + ty * 4]);
                const float4 e0 = *reinterpret_cast<const float4*>(&es[h * (BN + PADE) + tx * 4]);
                const float4 e1 = *reinterpret_cast<const float4*>(&es[h * (BN + PADE) + 64 + tx * 4]);
                const float zrv[4] = {zr.x, zr.y, zr.z, zr.w};
                const float ev[8]  = {e0.x, e0.y, e0.z, e0.w, e1.x, e1.y, e1.z, e1.w};
                #pragma unroll
                for (int i = 0; i < 4; ++i)
                    #pragma unroll
                    for (int j = 0; j < 8; ++j)
                        acc[i][j] = fmaf(zrv[i], ev[j], acc[i][j]);
            }
        }
        #pragma unroll
        for (int j = 0; j < 8; ++j) {
            const int code = nt * BN + (j < 4 ? tx * 4 + j : 64 + tx * 4 + (j - 4));
            const float e2v = e2[code];
            #pragma unroll
            for (int i = 0; i < 4; ++i) {
                const float d = __fadd_rn(__fmaf_rn(-2.f, acc[i][j], x2r[i]), e2v);
                if (d < best[i])       { best2[i] = best[i]; best[i] = d; bidx[i] = code; }
                else if (d < best2[i]) { best2[i] = d; }
            }
        }
    }

    __syncthreads();
    #pragma unroll
    for (int i = 0; i < 4; ++i) {
        bd [ty * 4 + i][tx] = best[i];
        bd2[ty * 4 + i][tx] = best2[i];
        bi [ty * 4 + i][tx] = bidx[i];
    }
    __syncthreads();
    if (threadIdx.x < BM) {
        const int r = threadIdx.x;
        float g1 = bd[r][0]; int gi = bi[r][0]; float g2 = bd2[r][0];
        #pragma unroll
        for (int t = 1; t < 16; ++t) {
            const float v = bd[r][t]; const int x = bi[r][t];
            if (v < g1)       { g2 = g1; g1 = v; gi = x; }
            else if (v == g1) { g2 = g1; if (x < gi) gi = x; }
            else              { g2 = fminf(g2, v); }
            g2 = fminf(g2, bd2[r][t]);
        }
        idx_i[row0 + r] = gi;
        idx_f[row0 + r] = (float)gi;
        if (g2 - g1 < TAU) {
            const int p = atomicAdd(flag_count, 1);
            if (p < MAXFLAG) flag_rows[p] = row0 + r;
        }
    }
}

// ---------------------------------------------------------------------------
// fixup stage 1: per (flagged row, code-quarter) block — fp64 ideal-g rescore
// ---------------------------------------------------------------------------
__global__ __launch_bounds__(256) void fixup_scan_kernel(
    const float* __restrict__ z, const float* __restrict__ emb,
    const float* __restrict__ x2, const float* __restrict__ e2,
    const int* __restrict__ flag_count, const int* __restrict__ flag_rows,
    float* __restrict__ qb1, int* __restrict__ qix)
{
    __shared__ float zrow[H_DIM];
    __shared__ float sd[256];
    __shared__ int   si[256];
    int n = *flag_count; if (n > MAXFLAG) n = MAXFLAG;
    const int q = blockIdx.x & 3;
    for (int j = blockIdx.x >> 2; j < n; j += (gridDim.x >> 2)) {
        const int row = flag_rows[j];
        __syncthreads();
        for (int h = threadIdx.x; h < H_DIM; h += 256)
            zrow[h] = z[(size_t)row * H_DIM + h];
        __syncthreads();
        const float x2r = x2[row];
        float bdv = 3.4e38f; int biv = 0x7fffffff;
        for (int k = q * 2048 + threadIdx.x; k < q * 2048 + 2048; k += 256) {
            const float* ek = emb + (size_t)k * H_DIM;
            double d0 = 0.0, d1 = 0.0, d2 = 0.0, d3 = 0.0;
            for (int h = 0; h < H_DIM; h += 4) {
                const float4 ev = *reinterpret_cast<const float4*>(ek + h);
                const float4 zv = *reinterpret_cast<const float4*>(&zrow[h]);
                d0 = fma((double)zv.x, (double)ev.x, d0);
                d1 = fma((double)zv.y, (double)ev.y, d1);
                d2 = fma((double)zv.z, (double)ev.z, d2);
                d3 = fma((double)zv.w, (double)ev.w, d3);
            }
            const float gf = (float)((d0 + d1) + (d2 + d3));
            const float d = __fadd_rn(__fmaf_rn(-2.f, gf, x2r), e2[k]);
            if (d < bdv) { bdv = d; biv = k; }
        }
        sd[threadIdx.x] = bdv; si[threadIdx.x] = biv;
        __syncthreads();
        for (int s = 128; s; s >>= 1) {
            if (threadIdx.x < s) {
                const float od = sd[threadIdx.x + s]; const int oi = si[threadIdx.x + s];
                if (od < sd[threadIdx.x] ||
                    (od == sd[threadIdx.x] && oi < si[threadIdx.x])) {
                    sd[threadIdx.x] = od; si[threadIdx.x] = oi;
                }
            }
            __syncthreads();
        }
        if (threadIdx.x == 0) { qb1[j * 4 + q] = sd[0]; qix[j * 4 + q] = si[0]; }
        __syncthreads();
    }
}

__global__ __launch_bounds__(256) void fixup_merge_kernel(
    const int* __restrict__ flag_count, const int* __restrict__ flag_rows,
    const float* __restrict__ qb1, const int* __restrict__ qix,
    int* __restrict__ idx_i, float* __restrict__ idx_f)
{
    int n = *flag_count; if (n > MAXFLAG) n = MAXFLAG;
    const int t = blockIdx.x * 256 + threadIdx.x;
    if (t >= n) return;
    float b = qb1[t * 4]; int ix = qix[t * 4];
    #pragma unroll
    for (int q = 1; q < 4; ++q) {
        const float ob = qb1[t * 4 + q];
        if (ob < b) { b = ob; ix = qix[t * 4 + q]; }
    }
    idx_i[flag_rows[t]] = ix;
    idx_f[flag_rows[t]] = (float)ix;
}

// ---------------------------------------------------------------------------
// z_st = z + (z_q - z) + both losses; float4 vectorized
// ---------------------------------------------------------------------------
__global__ __launch_bounds__(256) void epilogue_kernel(
    const float* __restrict__ z, const float* __restrict__ emb,
    const int* __restrict__ idx_i,
    float* __restrict__ z_st, float* __restrict__ loss_slots)
{
    const int NQ = M_ROWS * (H_DIM / 4);
    const float4* z4 = reinterpret_cast<const float4*>(z);
    const float4* e4 = reinterpret_cast<const float4*>(emb);
    float4* o4 = reinterpret_cast<float4*>(z_st);
    float local = 0.f;
    for (int q = blockIdx.x * 256 + threadIdx.x; q < NQ; q += gridDim.x * 256) {
        const int r  = q >> 7;
        const int h4 = q & 127;
        const float4 zq = e4[(size_t)idx_i[r] * 128 + h4];
        const float4 zv = z4[q];
        float4 t, o;
        t.x = zq.x - zv.x; o.x = zv.x + t.x;
        t.y = zq.y - zv.y; o.y = zv.y + t.y;
        t.z = zq.z - zv.z; o.z = zv.z + t.z;
        t.w = zq.w - zv.w; o.w = zv.w + t.w;
        o4[q] = o;
        local = fmaf(t.x, t.x, local);
        local = fmaf(t.y, t.y, local);
        local = fmaf(t.z, t.z, local);
        local = fmaf(t.w, t.w, local);
    }
    #pragma unroll
    for (int off = 32; off; off >>= 1) local += __shfl_down(local, off);
    __shared__ float part[4];
    const int lane = threadIdx.x & 63, wid = threadIdx.x >> 6;
    if (lane == 0) part[wid] = local;
    __syncthreads();
    if (threadIdx.x == 0) {
        const float s = (part[0] + part[1] + part[2] + part[3])
                        * (1.f / (float)((size_t)M_ROWS * H_DIM));
        atomicAdd(&loss_slots[0], s);
        atomicAdd(&loss_slots[1], s);
    }
}

// ---------------------------------------------------------------------------
extern "C" void kernel_launch(void* const* d_in, const int* in_sizes, int n_in,
                              void* d_out, int out_size, void* d_ws, size_t ws_size,
                              hipStream_t stream) {
    const float* z   = (const float*)d_in[0];
    const float* emb = (const float*)d_in[1];

    float* out   = (float*)d_out;
    float* z_st  = out;
    float* idx_f = out + (size_t)M_ROWS * H_DIM;
    float* loss  = out + (size_t)M_ROWS * H_DIM + M_ROWS;

    // scratch living temporarily in the z_st output region (dead until epilogue)
    float* pb1  = z_st;
    float* pb2  = z_st + (size_t)32 * M_ROWS;
    int*   pidx = (int*)(z_st + (size_t)64 * M_ROWS);
    float* qb1  = z_st + (size_t)96 * M_ROWS;
    int*   qix  = (int*)(z_st + (size_t)96 * M_ROWS + 4 * MAXFLAG);

    char* ws = (char*)d_ws;
    float* e2     = (float*)(ws + 0);
    float* x2     = (float*)(ws + 32768);
    int*   idx_i  = (int*)  (ws + 163840);
    int*   fcount = (int*)  (ws + 294912);
    int*   frows  = (int*)  (ws + 294976);
    unsigned short* zh = (unsigned short*)(ws + 426048);
    unsigned short* zl = (unsigned short*)(ws + 426048 + 33554432ull);
    unsigned short* eh = (unsigned short*)(ws + 426048 + 67108864ull);
    unsigned short* el = (unsigned short*)(ws + 426048 + 75497472ull);
    const size_t REQ = 426048ull + 83886080ull;   // ~80.4 MB

    hipLaunchKernelGGL(rowsq_all_kernel, dim3((M_ROWS + K_CODES) / 8), dim3(256), 0, stream,
                       z, emb, x2, e2, loss, fcount);

    if (ws_size >= REQ) {
        const int totq = (M_ROWS * H_DIM + K_CODES * H_DIM) / 4;
        hipLaunchKernelGGL(split_all_kernel, dim3(totq / 256), dim3(256), 0, stream,
                           z, emb, zh, zl, eh, el);
        hipLaunchKernelGGL(mfma_dist_kernel, dim3(4096), dim3(512), 0, stream,
                           zh, zl, eh, el, x2, e2, pb1, pb2, pidx);
        hipLaunchKernelGGL(combine_kernel, dim3(M_ROWS / 256), dim3(256), 0, stream,
                           pb1, pb2, pidx, idx_i, idx_f, fcount, frows);
    } else {
        hipLaunchKernelGGL(dist_argmin_kernel, dim3(M_ROWS / BM), dim3(256), 0, stream,
                           z, emb, x2, e2, idx_i, idx_f, fcount, frows);
    }

    hipLaunchKernelGGL(fixup_scan_kernel, dim3(8192), dim3(256), 0, stream,
                       z, emb, x2, e2, fcount, frows, qb1, qix);
    hipLaunchKernelGGL(fixup_merge_kernel, dim3(MAXFLAG / 256), dim3(256), 0, stream,
                       fcount, frows, qb1, qix, idx_i, idx_f);
    hipLaunchKernelGGL(epilogue_kernel, dim3(2048), dim3(256), 0, stream,
                       z, emb, idx_i, z_st, loss);
}

// Round 11
// 1169.508 us; speedup vs baseline: 1.3534x; 1.3534x over previous
//
#include <hip/hip_runtime.h>
#include <cstdint>
#include <cstddef>

#define M_ROWS 32768   // B*T
#define K_CODES 8192
#define H_DIM 512
#define TAU 2.5e-4f
#define MAXFLAG 32768

typedef float  f32x4 __attribute__((ext_vector_type(4)));
typedef short  s16x8 __attribute__((ext_vector_type(8)));

typedef __attribute__((address_space(3))) void as3_void;
typedef const __attribute__((address_space(1))) void as1_cvoid;
#define GLD16(gp, lp) __builtin_amdgcn_global_load_lds((as1_cvoid*)(gp), (as3_void*)(lp), 16, 0, 0)

// ---------------------------------------------------------------------------
// bf16 split helpers (RNE)
// ---------------------------------------------------------------------------
__device__ __forceinline__ unsigned short f2bf(float f) {
    uint32_t u = __float_as_uint(f);
    u = u + 0x7fffu + ((u >> 16) & 1u);
    return (unsigned short)(u >> 16);
}
__device__ __forceinline__ float bf2f(unsigned short h) {
    return __uint_as_float(((uint32_t)h) << 16);
}

// ---------------------------------------------------------------------------
// numpy pairwise sum-of-squares (bit-exact), 32 lanes per row.
// numpy: x2 = (B0+B1)+(B2+B3), B = 8-acc blocked 128-sum. fp32 add is
// bitwise-commutative so xor-shuffle pairing is exact.
// ---------------------------------------------------------------------------
__device__ __forceinline__ float np_sumsq_row32(const float* row, int lane32) {
    const int c = lane32 >> 3, j = lane32 & 7;
    const float* p = row + c * 128 + j;
    float s = __fmul_rn(p[0], p[0]);
    #pragma unroll
    for (int t = 1; t < 16; ++t) {
        const float v = p[8 * t];
        s = __fadd_rn(s, __fmul_rn(v, v));
    }
    s = __fadd_rn(s, __shfl_xor(s, 1));
    s = __fadd_rn(s, __shfl_xor(s, 2));
    s = __fadd_rn(s, __shfl_xor(s, 4));
    s = __fadd_rn(s, __shfl_xor(s, 8));
    s = __fadd_rn(s, __shfl_xor(s, 16));
    return s;
}

// ---------------------------------------------------------------------------
// FUSED prep: one pass over z and emb -> bf16 hi/lo split (optional) AND
// np-exact row sum-of-squares (x2 / e2), via an LDS row stage. 8 rows/block.
// ---------------------------------------------------------------------------
__global__ __launch_bounds__(256) void prep_kernel(
    const float* __restrict__ z, const float* __restrict__ emb,
    unsigned short* __restrict__ zh, unsigned short* __restrict__ zl,
    unsigned short* __restrict__ eh, unsigned short* __restrict__ el,
    float* __restrict__ x2, float* __restrict__ e2,
    float* __restrict__ loss_slots, int* __restrict__ flag_count, int do_split)
{
    __shared__ float zr[8][512];   // 16 KiB
    const int row0 = blockIdx.x * 8;

    #pragma unroll
    for (int k = 0; k < 4; ++k) {
        const int f  = threadIdx.x + k * 256;   // 0..1023 float4 slots
        const int r  = f >> 7;                  // local row 0..7
        const int c4 = f & 127;                 // float4 col
        const int grow = row0 + r;
        const float* src; unsigned short* hi; unsigned short* lo; size_t off;
        if (grow < M_ROWS) { src = z;   hi = zh; lo = zl; off = (size_t)grow * H_DIM; }
        else               { src = emb; hi = eh; lo = el; off = (size_t)(grow - M_ROWS) * H_DIM; }
        const float4 v = *reinterpret_cast<const float4*>(src + off + (size_t)c4 * 4);
        zr[r][c4 * 4 + 0] = v.x;
        zr[r][c4 * 4 + 1] = v.y;
        zr[r][c4 * 4 + 2] = v.z;
        zr[r][c4 * 4 + 3] = v.w;
        if (do_split) {
            ushort4 h, l;
            h.x = f2bf(v.x); l.x = f2bf(v.x - bf2f(h.x));
            h.y = f2bf(v.y); l.y = f2bf(v.y - bf2f(h.y));
            h.z = f2bf(v.z); l.z = f2bf(v.z - bf2f(h.z));
            h.w = f2bf(v.w); l.w = f2bf(v.w - bf2f(h.w));
            *reinterpret_cast<ushort4*>(hi + off + (size_t)c4 * 4) = h;
            *reinterpret_cast<ushort4*>(lo + off + (size_t)c4 * 4) = l;
        }
    }
    __syncthreads();

    const int r = threadIdx.x >> 5;   // 0..7
    const float s = np_sumsq_row32(&zr[r][0], threadIdx.x & 31);
    if ((threadIdx.x & 31) == 0) {
        const int grow = row0 + r;
        if (grow < M_ROWS) x2[grow] = s;
        else               e2[grow - M_ROWS] = s;
    }
    if (blockIdx.x == 0) {
        if (threadIdx.x < 2) loss_slots[threadIdx.x] = 0.f;
        if (threadIdx.x == 0) *flag_count = 0;
    }
}

// ---------------------------------------------------------------------------
// top-2 merge helper (tie -> lower index)
// ---------------------------------------------------------------------------
__device__ __forceinline__ void top2_merge(float& b1, int& ix, float& b2,
                                           float ob1, int oix, float ob2) {
    if (ob1 < b1)      { b2 = fminf(b1, ob2); b1 = ob1; ix = oix; }
    else if (ob1 > b1) { b2 = fminf(b2, ob1); }
    else               { if (oix < ix) ix = oix; b2 = b1; }
}

// ---------------------------------------------------------------------------
// MFMA distance GEMM + top-2 argmin — r9 VERIFIED kernel (16x16x32 bf16,
// 256x256 tile, 8 waves, BK=32, dbuf 128 KB, counted vmcnt(8) + raw
// barriers, product-major MFMA groups, 0 bank conflicts, 1020 us).
// ---------------------------------------------------------------------------
__global__ __launch_bounds__(512, 1) void mfma_dist_kernel(
    const unsigned short* __restrict__ zh, const unsigned short* __restrict__ zl,
    const unsigned short* __restrict__ eh, const unsigned short* __restrict__ el,
    const float* __restrict__ x2, const float* __restrict__ e2,
    float* __restrict__ pb1, float* __restrict__ pb2, int* __restrict__ pidx)
{
    __shared__ __align__(16) unsigned short lb[2][4][8192];   // 128 KiB

    const int tid = threadIdx.x;
    const int l   = tid & 63;
    const int w   = tid >> 6;          // 0..7
    const int wm  = w >> 2;            // 0..1  (row half)
    const int wn  = w & 3;             // 0..3  (code quarter)

    // XCD-banded block swizzle
    const int bid  = blockIdx.x;
    const int xcd  = bid & 7;
    const int sq   = bid >> 3;
    const int band = sq >> 7;
    const int r128 = sq & 127;
    const int ct   = r128 >> 2;
    const int rt   = (band * 8 + xcd) * 4 + (r128 & 3);
    const int row0 = rt * 256;
    const int c0   = ct * 256;

    // staging: wave w stages matrix m = w>>1, row-half = w&1
    const int m    = w >> 1;           // 0=Ah 1=Al 2=Bh 3=Bl
    const int half = w & 1;
    const unsigned short* sp = (m == 0) ? zh : (m == 1) ? zl : (m == 2) ? eh : el;
    const int rbase0 = (m < 2) ? row0 : c0;
    const unsigned short* sb = sp
        + (size_t)(rbase0 + half * 128 + (l >> 2)) * H_DIM
        + ((l & 3) ^ ((l >> 3) & 3)) * 8;

    // ds_read geometry (swizzled, verified r5-r9)
    const int aoff = (wm * 128 + (l & 15)) * 64 + (((l >> 4) ^ ((l >> 1) & 3)) * 16);
    const int boff = (wn * 64  + (l & 15)) * 64 + (((l >> 4) ^ ((l >> 1) & 3)) * 16);

    f32x4 acc[8][4];
    #pragma unroll
    for (int i = 0; i < 8; ++i)
        #pragma unroll
        for (int j = 0; j < 4; ++j)
            acc[i][j] = (f32x4){0.f, 0.f, 0.f, 0.f};

    // prologue: stage step 0 into parity 0
    {
        char* dst = (char*)&lb[0][m][0] + half * 8192;
        #pragma unroll
        for (int t = 0; t < 8; ++t)
            GLD16(sb + (size_t)t * 16 * H_DIM, dst + t * 1024);
    }
    asm volatile("s_waitcnt vmcnt(0)" ::: "memory");
    __builtin_amdgcn_s_barrier();

    for (int s = 0; s < 16; ++s) {
        const int par = s & 1;

        if (s < 15) {
            const unsigned short* src = sb + (s + 1) * 32;
            char* dst = (char*)&lb[par ^ 1][m][0] + half * 8192;
            #pragma unroll
            for (int t = 0; t < 8; ++t)
                GLD16(src + (size_t)t * 16 * H_DIM, dst + t * 1024);
            asm volatile("s_waitcnt vmcnt(8)" ::: "memory");   // oldest 8 = this step's data
        } else {
            asm volatile("s_waitcnt vmcnt(0)" ::: "memory");
        }
        __builtin_amdgcn_s_barrier();

        const char* pAh = (const char*)&lb[par][0][0];
        const char* pAl = (const char*)&lb[par][1][0];
        const char* pBh = (const char*)&lb[par][2][0];
        const char* pBl = (const char*)&lb[par][3][0];

        s16x8 ah[8];
        #pragma unroll
        for (int i = 0; i < 8; ++i)
            ah[i] = *(const s16x8*)(pAh + aoff + i * 1024);
        s16x8 bh[4], bv[4];
        #pragma unroll
        for (int j = 0; j < 4; ++j) {
            bh[j] = *(const s16x8*)(pBh + boff + j * 1024);
            bv[j] = *(const s16x8*)(pBl + boff + j * 1024);
        }

        __builtin_amdgcn_s_setprio(1);
        // G1: ah x bv — 32 independent
        #pragma unroll
        for (int j = 0; j < 4; ++j)
            #pragma unroll
            for (int i = 0; i < 8; ++i)
                acc[i][j] = __builtin_amdgcn_mfma_f32_16x16x32_bf16(ah[i], bv[j], acc[i][j], 0, 0, 0);
        // late-load Al first half (latency hidden under G2)
        s16x8 avA[4];
        #pragma unroll
        for (int i = 0; i < 4; ++i)
            avA[i] = *(const s16x8*)(pAl + aoff + i * 1024);
        // G2: ah x bh — 32 independent
        #pragma unroll
        for (int j = 0; j < 4; ++j)
            #pragma unroll
            for (int i = 0; i < 8; ++i)
                acc[i][j] = __builtin_amdgcn_mfma_f32_16x16x32_bf16(ah[i], bh[j], acc[i][j], 0, 0, 0);
        // late-load Al second half
        s16x8 avB[4];
        #pragma unroll
        for (int i = 0; i < 4; ++i)
            avB[i] = *(const s16x8*)(pAl + aoff + (4 + i) * 1024);
        // G3a: avA x bh
        #pragma unroll
        for (int j = 0; j < 4; ++j)
            #pragma unroll
            for (int i = 0; i < 4; ++i)
                acc[i][j] = __builtin_amdgcn_mfma_f32_16x16x32_bf16(avA[i], bh[j], acc[i][j], 0, 0, 0);
        // G3b: avB x bh
        #pragma unroll
        for (int j = 0; j < 4; ++j)
            #pragma unroll
            for (int i = 0; i < 4; ++i)
                acc[4 + i][j] = __builtin_amdgcn_mfma_f32_16x16x32_bf16(avB[i], bh[j], acc[4 + i][j], 0, 0, 0);
        __builtin_amdgcn_s_setprio(0);

        __builtin_amdgcn_s_barrier();   // all reads of par done -> next GLD safe
    }

    // fold: np-order d = fl(fl(x2-2g)+e2), top-2 over j, 16-lane merge, LDS merge
    float* mb1 = (float*)&lb[0][0][0];   // [4][256]
    float* mb2 = mb1 + 1024;
    int*   mi  = (int*)(mb1 + 2048);

    float e2v[4];
    #pragma unroll
    for (int j = 0; j < 4; ++j)
        e2v[j] = e2[c0 + wn * 64 + j * 16 + (l & 15)];

    #pragma unroll
    for (int i = 0; i < 8; ++i) {
        const float4 x2v = *reinterpret_cast<const float4*>(
            x2 + row0 + wm * 128 + i * 16 + (l >> 4) * 4);
        const float x2a[4] = {x2v.x, x2v.y, x2v.z, x2v.w};
        #pragma unroll
        for (int r = 0; r < 4; ++r) {
            float b1 = 3.4e38f, b2 = 3.4e38f; int ix = 0;
            #pragma unroll
            for (int j = 0; j < 4; ++j) {
                const float d = __fadd_rn(__fmaf_rn(-2.f, acc[i][j][r], x2a[r]), e2v[j]);
                const int cj = c0 + wn * 64 + j * 16 + (l & 15);
                if (d < b1)      { b2 = b1; b1 = d; ix = cj; }
                else if (d < b2) { b2 = d; }
            }
            #pragma unroll
            for (int mm = 1; mm <= 8; mm <<= 1) {
                const float ob1 = __shfl_xor(b1, mm);
                const float ob2 = __shfl_xor(b2, mm);
                const int   oix = __shfl_xor(ix, mm);
                top2_merge(b1, ix, b2, ob1, oix, ob2);
            }
            if ((l & 15) == 0) {
                const int rl = wm * 128 + i * 16 + (l >> 4) * 4 + r;
                mb1[wn * 256 + rl] = b1;
                mb2[wn * 256 + rl] = b2;
                mi [wn * 256 + rl] = ix;
            }
        }
    }
    __syncthreads();
    if (tid < 256) {
        float b1 = mb1[tid], b2 = mb2[tid]; int ix = mi[tid];
        #pragma unroll
        for (int q = 1; q < 4; ++q)
            top2_merge(b1, ix, b2, mb1[q * 256 + tid], mi[q * 256 + tid], mb2[q * 256 + tid]);
        const size_t o = (size_t)ct * M_ROWS + row0 + tid;
        pb1[o] = b1; pb2[o] = b2; pidx[o] = ix;
    }
}

// merge the 32 code-split partials per row; emit idx + ambiguity flags
__global__ __launch_bounds__(256) void combine_kernel(
    const float* __restrict__ pb1, const float* __restrict__ pb2,
    const int* __restrict__ pidx,
    int* __restrict__ idx_i, float* __restrict__ idx_f,
    int* __restrict__ flag_count, int* __restrict__ flag_rows)
{
    const int r = blockIdx.x * 256 + threadIdx.x;
    if (r >= M_ROWS) return;
    float b1 = pb1[r], b2 = pb2[r]; int ix = pidx[r];
    #pragma unroll 4
    for (int ct = 1; ct < 32; ++ct)
        top2_merge(b1, ix, b2, pb1[(size_t)ct * M_ROWS + r],
                   pidx[(size_t)ct * M_ROWS + r], pb2[(size_t)ct * M_ROWS + r]);
    idx_i[r] = ix;
    idx_f[r] = (float)ix;
    if (b2 - b1 < TAU) {
        const int p = atomicAdd(flag_count, 1);
        if (p < MAXFLAG) flag_rows[p] = r;
    }
}

// ---------------------------------------------------------------------------
// FALLBACK (round-3 fp32 path) — only if ws_size too small
// ---------------------------------------------------------------------------
#define BM 64
#define BN 128
#define BH 32
#define PADZ 4
#define PADE 4

__device__ __forceinline__ void stage_transposed(const float* __restrict__ src,
                                                 int row0, int h0,
                                                 float* lds, int R, int ldp) {
    const int nf4 = R * (BH / 4);
    for (int f = threadIdx.x; f < nf4; f += 256) {
        const int r  = f / (BH / 4);
        const int c4 = (f % (BH / 4)) * 4;
        const float4 v = *reinterpret_cast<const float4*>(
            src + (size_t)(row0 + r) * H_DIM + h0 + c4);
        lds[(c4 + 0) * ldp + r] = v.x;
        lds[(c4 + 1) * ldp + r] = v.y;
        lds[(c4 + 2) * ldp + r] = v.z;
        lds[(c4 + 3) * ldp + r] = v.w;
    }
}

__global__ __launch_bounds__(256) void dist_argmin_kernel(
    const float* __restrict__ z, const float* __restrict__ emb,
    const float* __restrict__ x2, const float* __restrict__ e2,
    int* __restrict__ idx_i, float* __restrict__ idx_f,
    int* __restrict__ flag_count, int* __restrict__ flag_rows)
{
    __shared__ float zs[BH * (BM + PADZ)];
    __shared__ float es[BH * (BN + PADE)];
    __shared__ float bd[BM][17];
    __shared__ float bd2[BM][17];
    __shared__ int   bi[BM][17];

    const int row0 = blockIdx.x * BM;
    const int tx = threadIdx.x & 15;
    const int ty = threadIdx.x >> 4;

    float x2r[4];
    #pragma unroll
    for (int i = 0; i < 4; ++i) x2r[i] = x2[row0 + ty * 4 + i];

    float best[4], best2[4];
    int   bidx[4];
    #pragma unroll
    for (int i = 0; i < 4; ++i) { best[i] = 3.4e38f; best2[i] = 3.4e38f; bidx[i] = 0; }

    for (int nt = 0; nt < K_CODES / BN; ++nt) {
        float acc[4][8];
        #pragma unroll
        for (int i = 0; i < 4; ++i)
            #pragma unroll
            for (int j = 0; j < 8; ++j) acc[i][j] = 0.f;

        for (int hc = 0; hc < H_DIM / BH; ++hc) {
            __syncthreads();
            stage_transposed(z,   row0,    hc * BH, zs, BM, BM + PADZ);
            stage_transposed(emb, nt * BN, hc * BH, es, BN, BN + PADE);
            __syncthreads();
            #pragma unroll
            for (int h = 0; h < BH; ++h) {
                const float4 zr = *reinterpret_cast<const float4*>(&zs[h * (BM + PADZ) + ty * 4]);
                const float4 e0 = *reinterpret_cast<const float4*>(&es[h * (BN + PADE) + tx * 4]);
                const float4 e1 = *reinterpret_cast<const float4*>(&es[h * (BN + PADE) + 64 + tx * 4]);
                const float zrv[4] = {zr.x, zr.y, zr.z, zr.w};
                const float ev[8]  = {e0.x, e0.y, e0.z, e0.w, e1.x, e1.y, e1.z, e1.w};
                #pragma unroll
                for (int i = 0; i < 4; ++i)
                    #pragma unroll
                    for (int j = 0; j < 8; ++j)
                        acc[i][j] = fmaf(zrv[i], ev[j], acc[i][j]);
            }
        }
        #pragma unroll
        for (int j = 0; j < 8; ++j) {
            const int code = nt * BN + (j < 4 ? tx * 4 + j : 64 + tx * 4 + (j - 4));
            const float e2v = e2[code];
            #pragma unroll
            for (int i = 0; i < 4; ++i) {
                const float d = __fadd_rn(__fmaf_rn(-2.f, acc[i][j], x2r[i]), e2v);
                if (d < best[i])       { best2[i] = best[i]; best[i] = d; bidx[i] = code; }
                else if (d < best2[i]) { best2[i] = d; }
            }
        }
    }

    __syncthreads();
    #pragma unroll
    for (int i = 0; i < 4; ++i) {
        bd [ty * 4 + i][tx] = best[i];
        bd2[ty * 4 + i][tx] = best2[i];
        bi [ty * 4 + i][tx] = bidx[i];
    }
    __syncthreads();
    if (threadIdx.x < BM) {
        const int r = threadIdx.x;
        float g1 = bd[r][0]; int gi = bi[r][0]; float g2 = bd2[r][0];
        #pragma unroll
        for (int t = 1; t < 16; ++t) {
            const float v = bd[r][t]; const int x = bi[r][t];
            if (v < g1)       { g2 = g1; g1 = v; gi = x; }
            else if (v == g1) { g2 = g1; if (x < gi) gi = x; }
            else              { g2 = fminf(g2, v); }
            g2 = fminf(g2, bd2[r][t]);
        }
        idx_i[row0 + r] = gi;
        idx_f[row0 + r] = (float)gi;
        if (g2 - g1 < TAU) {
            const int p = atomicAdd(flag_count, 1);
            if (p < MAXFLAG) flag_rows[p] = row0 + r;
        }
    }
}

// ---------------------------------------------------------------------------
// fixup stage 1: per (flagged row, code-quarter) block — fp64 ideal-g rescore
// ---------------------------------------------------------------------------
__global__ __launch_bounds__(256) void fixup_scan_kernel(
    const float* __restrict__ z, const float* __restrict__ emb,
    const float* __restrict__ x2, const float* __restrict__ e2,
    const int* __restrict__ flag_count, const int* __restrict__ flag_rows,
    float* __restrict__ qb1, int* __restrict__ qix)
{
    __shared__ float zrow[H_DIM];
    __shared__ float sd[256];
    __shared__ int   si[256];
    int n = *flag_count; if (n > MAXFLAG) n = MAXFLAG;
    const int q = blockIdx.x & 3;
    for (int j = blockIdx.x >> 2; j < n; j += (gridDim.x >> 2)) {
        const int row = flag_rows[j];
        __syncthreads();
        for (int h = threadIdx.x; h < H_DIM; h += 256)
            zrow[h] = z[(size_t)row * H_DIM + h];
        __syncthreads();
        const float x2r = x2[row];
        float bdv = 3.4e38f; int biv = 0x7fffffff;
        for (int k = q * 2048 + threadIdx.x; k < q * 2048 + 2048; k += 256) {
            const float* ek = emb + (size_t)k * H_DIM;
            double d0 = 0.0, d1 = 0.0, d2 = 0.0, d3 = 0.0;
            for (int h = 0; h < H_DIM; h += 4) {
                const float4 ev = *reinterpret_cast<const float4*>(ek + h);
                const float4 zv = *reinterpret_cast<const float4*>(&zrow[h]);
                d0 = fma((double)zv.x, (double)ev.x, d0);
                d1 = fma((double)zv.y, (double)ev.y, d1);
                d2 = fma((double)zv.z, (double)ev.z, d2);
                d3 = fma((double)zv.w, (double)ev.w, d3);
            }
            const float gf = (float)((d0 + d1) + (d2 + d3));
            const float d = __fadd_rn(__fmaf_rn(-2.f, gf, x2r), e2[k]);
            if (d < bdv) { bdv = d; biv = k; }
        }
        sd[threadIdx.x] = bdv; si[threadIdx.x] = biv;
        __syncthreads();
        for (int s = 128; s; s >>= 1) {
            if (threadIdx.x < s) {
                const float od = sd[threadIdx.x + s]; const int oi = si[threadIdx.x + s];
                if (od < sd[threadIdx.x] ||
                    (od == sd[threadIdx.x] && oi < si[threadIdx.x])) {
                    sd[threadIdx.x] = od; si[threadIdx.x] = oi;
                }
            }
            __syncthreads();
        }
        if (threadIdx.x == 0) { qb1[j * 4 + q] = sd[0]; qix[j * 4 + q] = si[0]; }
        __syncthreads();
    }
}

__global__ __launch_bounds__(256) void fixup_merge_kernel(
    const int* __restrict__ flag_count, const int* __restrict__ flag_rows,
    const float* __restrict__ qb1, const int* __restrict__ qix,
    int* __restrict__ idx_i, float* __restrict__ idx_f)
{
    int n = *flag_count; if (n > MAXFLAG) n = MAXFLAG;
    const int t = blockIdx.x * 256 + threadIdx.x;
    if (t >= n) return;
    float b = qb1[t * 4]; int ix = qix[t * 4];
    #pragma unroll
    for (int q = 1; q < 4; ++q) {
        const float ob = qb1[t * 4 + q];
        if (ob < b) { b = ob; ix = qix[t * 4 + q]; }
    }
    idx_i[flag_rows[t]] = ix;
    idx_f[flag_rows[t]] = (float)ix;
}

// ---------------------------------------------------------------------------
// z_st = z + (z_q - z) + both losses; float4 vectorized
// ---------------------------------------------------------------------------
__global__ __launch_bounds__(256) void epilogue_kernel(
    const float* __restrict__ z, const float* __restrict__ emb,
    const int* __restrict__ idx_i,
    float* __restrict__ z_st, float* __restrict__ loss_slots)
{
    const int NQ = M_ROWS * (H_DIM / 4);
    const float4* z4 = reinterpret_cast<const float4*>(z);
    const float4* e4 = reinterpret_cast<const float4*>(emb);
    float4* o4 = reinterpret_cast<float4*>(z_st);
    float local = 0.f;
    for (int q = blockIdx.x * 256 + threadIdx.x; q < NQ; q += gridDim.x * 256) {
        const int r  = q >> 7;
        const int h4 = q & 127;
        const float4 zq = e4[(size_t)idx_i[r] * 128 + h4];
        const float4 zv = z4[q];
        float4 t, o;
        t.x = zq.x - zv.x; o.x = zv.x + t.x;
        t.y = zq.y - zv.y; o.y = zv.y + t.y;
        t.z = zq.z - zv.z; o.z = zv.z + t.z;
        t.w = zq.w - zv.w; o.w = zv.w + t.w;
        o4[q] = o;
        local = fmaf(t.x, t.x, local);
        local = fmaf(t.y, t.y, local);
        local = fmaf(t.z, t.z, local);
        local = fmaf(t.w, t.w, local);
    }
    #pragma unroll
    for (int off = 32; off; off >>= 1) local += __shfl_down(local, off);
    __shared__ float part[4];
    const int lane = threadIdx.x & 63, wid = threadIdx.x >> 6;
    if (lane == 0) part[wid] = local;
    __syncthreads();
    if (threadIdx.x == 0) {
        const float s = (part[0] + part[1] + part[2] + part[3])
                        * (1.f / (float)((size_t)M_ROWS * H_DIM));
        atomicAdd(&loss_slots[0], s);
        atomicAdd(&loss_slots[1], s);
    }
}

// ---------------------------------------------------------------------------
extern "C" void kernel_launch(void* const* d_in, const int* in_sizes, int n_in,
                              void* d_out, int out_size, void* d_ws, size_t ws_size,
                              hipStream_t stream) {
    const float* z   = (const float*)d_in[0];
    const float* emb = (const float*)d_in[1];

    float* out   = (float*)d_out;
    float* z_st  = out;
    float* idx_f = out + (size_t)M_ROWS * H_DIM;
    float* loss  = out + (size_t)M_ROWS * H_DIM + M_ROWS;

    // scratch living temporarily in the z_st output region (dead until epilogue)
    float* pb1  = z_st;
    float* pb2  = z_st + (size_t)32 * M_ROWS;
    int*   pidx = (int*)(z_st + (size_t)64 * M_ROWS);
    float* qb1  = z_st + (size_t)96 * M_ROWS;
    int*   qix  = (int*)(z_st + (size_t)96 * M_ROWS + 4 * MAXFLAG);

    char* ws = (char*)d_ws;
    float* e2     = (float*)(ws + 0);
    float* x2     = (float*)(ws + 32768);
    int*   idx_i  = (int*)  (ws + 163840);
    int*   fcount = (int*)  (ws + 294912);
    int*   frows  = (int*)  (ws + 294976);
    unsigned short* zh = (unsigned short*)(ws + 426048);
    unsigned short* zl = (unsigned short*)(ws + 426048 + 33554432ull);
    unsigned short* eh = (unsigned short*)(ws + 426048 + 67108864ull);
    unsigned short* el = (unsigned short*)(ws + 426048 + 75497472ull);
    const size_t REQ = 426048ull + 83886080ull;   // ~80.4 MB

    const int use_mfma = (ws_size >= REQ) ? 1 : 0;

    hipLaunchKernelGGL(prep_kernel, dim3((M_ROWS + K_CODES) / 8), dim3(256), 0, stream,
                       z, emb, zh, zl, eh, el, x2, e2, loss, fcount, use_mfma);

    if (use_mfma) {
        hipLaunchKernelGGL(mfma_dist_kernel, dim3(4096), dim3(512), 0, stream,
                           zh, zl, eh, el, x2, e2, pb1, pb2, pidx);
        hipLaunchKernelGGL(combine_kernel, dim3(M_ROWS / 256), dim3(256), 0, stream,
                           pb1, pb2, pidx, idx_i, idx_f, fcount, frows);
    } else {
        hipLaunchKernelGGL(dist_argmin_kernel, dim3(M_ROWS / BM), dim3(256), 0, stream,
                           z, emb, x2, e2, idx_i, idx_f, fcount, frows);
    }

    hipLaunchKernelGGL(fixup_scan_kernel, dim3(8192), dim3(256), 0, stream,
                       z, emb, x2, e2, fcount, frows, qb1, qix);
    hipLaunchKernelGGL(fixup_merge_kernel, dim3(MAXFLAG / 256), dim3(256), 0, stream,
                       fcount, frows, qb1, qix, idx_i, idx_f);
    hipLaunchKernelGGL(epilogue_kernel, dim3(2048), dim3(256), 0, stream,
                       z, emb, idx_i, z_st, loss);
}

// Round 12
// 1142.411 us; speedup vs baseline: 1.3855x; 1.0237x over previous
//
#include <hip/hip_runtime.h>
#include <cstdint>
#include <cstddef>

#define M_ROWS 32768   // B*T
#define K_CODES 8192
#define H_DIM 512
#define TAU 2.5e-4f
#define MAXFLAG 32768

typedef float  f32x4 __attribute__((ext_vector_type(4)));
typedef short  s16x8 __attribute__((ext_vector_type(8)));

typedef __attribute__((address_space(3))) void as3_void;
typedef const __attribute__((address_space(1))) void as1_cvoid;
#define GLD16(gp, lp) __builtin_amdgcn_global_load_lds((as1_cvoid*)(gp), (as3_void*)(lp), 16, 0, 0)

// ---------------------------------------------------------------------------
// bf16 split helpers (RNE)
// ---------------------------------------------------------------------------
__device__ __forceinline__ unsigned short f2bf(float f) {
    uint32_t u = __float_as_uint(f);
    u = u + 0x7fffu + ((u >> 16) & 1u);
    return (unsigned short)(u >> 16);
}
__device__ __forceinline__ float bf2f(unsigned short h) {
    return __uint_as_float(((uint32_t)h) << 16);
}

// ---------------------------------------------------------------------------
// numpy pairwise sum-of-squares (bit-exact), 32 lanes per row.
// ---------------------------------------------------------------------------
__device__ __forceinline__ float np_sumsq_row32(const float* row, int lane32) {
    const int c = lane32 >> 3, j = lane32 & 7;
    const float* p = row + c * 128 + j;
    float s = __fmul_rn(p[0], p[0]);
    #pragma unroll
    for (int t = 1; t < 16; ++t) {
        const float v = p[8 * t];
        s = __fadd_rn(s, __fmul_rn(v, v));
    }
    s = __fadd_rn(s, __shfl_xor(s, 1));
    s = __fadd_rn(s, __shfl_xor(s, 2));
    s = __fadd_rn(s, __shfl_xor(s, 4));
    s = __fadd_rn(s, __shfl_xor(s, 8));
    s = __fadd_rn(s, __shfl_xor(s, 16));
    return s;
}

// ---------------------------------------------------------------------------
// FUSED prep (r11-verified): one pass over z and emb -> bf16 hi/lo split AND
// np-exact row sum-of-squares, via an LDS row stage. 8 rows/block.
// ---------------------------------------------------------------------------
__global__ __launch_bounds__(256) void prep_kernel(
    const float* __restrict__ z, const float* __restrict__ emb,
    unsigned short* __restrict__ zh, unsigned short* __restrict__ zl,
    unsigned short* __restrict__ eh, unsigned short* __restrict__ el,
    float* __restrict__ x2, float* __restrict__ e2,
    float* __restrict__ loss_slots, int* __restrict__ flag_count, int do_split)
{
    __shared__ float zr[8][512];   // 16 KiB
    const int row0 = blockIdx.x * 8;

    #pragma unroll
    for (int k = 0; k < 4; ++k) {
        const int f  = threadIdx.x + k * 256;
        const int r  = f >> 7;
        const int c4 = f & 127;
        const int grow = row0 + r;
        const float* src; unsigned short* hi; unsigned short* lo; size_t off;
        if (grow < M_ROWS) { src = z;   hi = zh; lo = zl; off = (size_t)grow * H_DIM; }
        else               { src = emb; hi = eh; lo = el; off = (size_t)(grow - M_ROWS) * H_DIM; }
        const float4 v = *reinterpret_cast<const float4*>(src + off + (size_t)c4 * 4);
        zr[r][c4 * 4 + 0] = v.x;
        zr[r][c4 * 4 + 1] = v.y;
        zr[r][c4 * 4 + 2] = v.z;
        zr[r][c4 * 4 + 3] = v.w;
        if (do_split) {
            ushort4 h, l;
            h.x = f2bf(v.x); l.x = f2bf(v.x - bf2f(h.x));
            h.y = f2bf(v.y); l.y = f2bf(v.y - bf2f(h.y));
            h.z = f2bf(v.z); l.z = f2bf(v.z - bf2f(h.z));
            h.w = f2bf(v.w); l.w = f2bf(v.w - bf2f(h.w));
            *reinterpret_cast<ushort4*>(hi + off + (size_t)c4 * 4) = h;
            *reinterpret_cast<ushort4*>(lo + off + (size_t)c4 * 4) = l;
        }
    }
    __syncthreads();

    const int r = threadIdx.x >> 5;
    const float s = np_sumsq_row32(&zr[r][0], threadIdx.x & 31);
    if ((threadIdx.x & 31) == 0) {
        const int grow = row0 + r;
        if (grow < M_ROWS) x2[grow] = s;
        else               e2[grow - M_ROWS] = s;
    }
    if (blockIdx.x == 0) {
        if (threadIdx.x < 2) loss_slots[threadIdx.x] = 0.f;
        if (threadIdx.x == 0) *flag_count = 0;
    }
}

// ---------------------------------------------------------------------------
// top-2 merge helper (tie -> lower index)
// ---------------------------------------------------------------------------
__device__ __forceinline__ void top2_merge(float& b1, int& ix, float& b2,
                                           float ob1, int oix, float ob2) {
    if (ob1 < b1)      { b2 = fminf(b1, ob2); b1 = ob1; ix = oix; }
    else if (ob1 > b1) { b2 = fminf(b2, ob1); }
    else               { if (oix < ix) ix = oix; b2 = b1; }
}

// ---------------------------------------------------------------------------
// MFMA distance GEMM + top-2 argmin — r8 VERIFIED kernel (best GEMM measured:
// 980 us, MfmaUtil 37.6, 0 bank conflicts). 256x256 tile, 8 waves, BK=32,
// dbuf 128 KB; each K-step = 4 phases {ds_read 2 A-frag pairs (+B in ph0);
// GLD pair in ph0/ph1; sched_barrier; s_barrier; lgkmcnt(0); sched_barrier;
// setprio(1); 24 MFMA; setprio(0); s_barrier}; vmcnt(0) only in phase 3 on
// loads issued 2-3 phases earlier.
// ---------------------------------------------------------------------------
__global__ __launch_bounds__(512, 1) void mfma_dist_kernel(
    const unsigned short* __restrict__ zh, const unsigned short* __restrict__ zl,
    const unsigned short* __restrict__ eh, const unsigned short* __restrict__ el,
    const float* __restrict__ x2, const float* __restrict__ e2,
    float* __restrict__ pb1, float* __restrict__ pb2, int* __restrict__ pidx)
{
    __shared__ __align__(16) unsigned short lb[2][4][8192];   // 128 KiB

    const int tid = threadIdx.x;
    const int l   = tid & 63;
    const int w   = tid >> 6;          // 0..7
    const int wm  = w >> 2;            // 0..1  (row half: 128 rows)
    const int wn  = w & 3;             // 0..3  (code quarter: 64 codes)

    // XCD-banded block swizzle
    const int bid  = blockIdx.x;
    const int xcd  = bid & 7;
    const int sq   = bid >> 3;
    const int band = sq >> 7;
    const int r128 = sq & 127;
    const int ct   = r128 >> 2;
    const int rt   = (band * 8 + xcd) * 4 + (r128 & 3);
    const int row0 = rt * 256;
    const int c0   = ct * 256;

    // staging: wave w stages matrix m = w>>1, row-half = w&1
    const int m    = w >> 1;           // 0=Ah 1=Al 2=Bh 3=Bl
    const int half = w & 1;
    const unsigned short* sp = (m == 0) ? zh : (m == 1) ? zl : (m == 2) ? eh : el;
    const int rbase0 = (m < 2) ? row0 : c0;
    const unsigned short* sb = sp
        + (size_t)(rbase0 + half * 128 + (l >> 2)) * H_DIM
        + ((l & 3) ^ ((l >> 3) & 3)) * 8;

    // ds_read geometry (swizzled, verified r5-r9)
    const int aoff = (wm * 128 + (l & 15)) * 64 + (((l >> 4) ^ ((l >> 1) & 3)) * 16);
    const int boff = (wn * 64  + (l & 15)) * 64 + (((l >> 4) ^ ((l >> 1) & 3)) * 16);

    f32x4 acc[8][4];
    #pragma unroll
    for (int i = 0; i < 8; ++i)
        #pragma unroll
        for (int j = 0; j < 4; ++j)
            acc[i][j] = (f32x4){0.f, 0.f, 0.f, 0.f};

    // prologue: stage step 0 into parity 0
    {
        char* dst = (char*)&lb[0][m][0] + half * 8192;
        #pragma unroll
        for (int t = 0; t < 8; ++t)
            GLD16(sb + (size_t)t * 16 * H_DIM, dst + t * 1024);
    }
    asm volatile("s_waitcnt vmcnt(0)" ::: "memory");
    __builtin_amdgcn_s_barrier();

#define MFMA_PAIR(I0, AH0, AV0, AH1, AV1)                                                        \
    _Pragma("unroll")                                                                            \
    for (int j = 0; j < 4; ++j) {                                                                \
        acc[I0][j]     = __builtin_amdgcn_mfma_f32_16x16x32_bf16(AV0, bh[j], acc[I0][j], 0,0,0); \
        acc[I0][j]     = __builtin_amdgcn_mfma_f32_16x16x32_bf16(AH0, bv[j], acc[I0][j], 0,0,0); \
        acc[I0][j]     = __builtin_amdgcn_mfma_f32_16x16x32_bf16(AH0, bh[j], acc[I0][j], 0,0,0); \
        acc[I0+1][j]   = __builtin_amdgcn_mfma_f32_16x16x32_bf16(AV1, bh[j], acc[I0+1][j], 0,0,0); \
        acc[I0+1][j]   = __builtin_amdgcn_mfma_f32_16x16x32_bf16(AH1, bv[j], acc[I0+1][j], 0,0,0); \
        acc[I0+1][j]   = __builtin_amdgcn_mfma_f32_16x16x32_bf16(AH1, bh[j], acc[I0+1][j], 0,0,0); \
    }

    for (int s = 0; s < 16; ++s) {
        const int par = s & 1;
        const char* pAh = (const char*)&lb[par][0][0];
        const char* pAl = (const char*)&lb[par][1][0];
        const char* pBh = (const char*)&lb[par][2][0];
        const char* pBl = (const char*)&lb[par][3][0];
        char* dst = (char*)&lb[par ^ 1][m][0] + half * 8192;
        const unsigned short* src = sb + (s + 1) * 32;
        const bool pf = (s < 15);

        s16x8 bh[4], bv[4];

        // ================= phase 0: B frags + A i=0,1; GLD t=0..3 ==========
        {
            #pragma unroll
            for (int j = 0; j < 4; ++j) {
                bh[j] = *(const s16x8*)(pBh + boff + j * 1024);
                bv[j] = *(const s16x8*)(pBl + boff + j * 1024);
            }
            const s16x8 a0h = *(const s16x8*)(pAh + aoff + 0 * 1024);
            const s16x8 a0v = *(const s16x8*)(pAl + aoff + 0 * 1024);
            const s16x8 a1h = *(const s16x8*)(pAh + aoff + 1 * 1024);
            const s16x8 a1v = *(const s16x8*)(pAl + aoff + 1 * 1024);
            if (pf) {
                GLD16(src + (size_t)0 * 16 * H_DIM, dst + 0 * 1024);
                GLD16(src + (size_t)1 * 16 * H_DIM, dst + 1 * 1024);
                GLD16(src + (size_t)2 * 16 * H_DIM, dst + 2 * 1024);
                GLD16(src + (size_t)3 * 16 * H_DIM, dst + 3 * 1024);
            }
            __builtin_amdgcn_sched_barrier(0);
            __builtin_amdgcn_s_barrier();
            asm volatile("s_waitcnt lgkmcnt(0)" ::: "memory");
            __builtin_amdgcn_sched_barrier(0);
            __builtin_amdgcn_s_setprio(1);
            MFMA_PAIR(0, a0h, a0v, a1h, a1v)
            __builtin_amdgcn_s_setprio(0);
            __builtin_amdgcn_s_barrier();
        }
        // ================= phase 1: A i=2,3; GLD t=4..7 ====================
        {
            const s16x8 a0h = *(const s16x8*)(pAh + aoff + 2 * 1024);
            const s16x8 a0v = *(const s16x8*)(pAl + aoff + 2 * 1024);
            const s16x8 a1h = *(const s16x8*)(pAh + aoff + 3 * 1024);
            const s16x8 a1v = *(const s16x8*)(pAl + aoff + 3 * 1024);
            if (pf) {
                GLD16(src + (size_t)4 * 16 * H_DIM, dst + 4 * 1024);
                GLD16(src + (size_t)5 * 16 * H_DIM, dst + 5 * 1024);
                GLD16(src + (size_t)6 * 16 * H_DIM, dst + 6 * 1024);
                GLD16(src + (size_t)7 * 16 * H_DIM, dst + 7 * 1024);
            }
            __builtin_amdgcn_sched_barrier(0);
            __builtin_amdgcn_s_barrier();
            asm volatile("s_waitcnt lgkmcnt(0)" ::: "memory");
            __builtin_amdgcn_sched_barrier(0);
            __builtin_amdgcn_s_setprio(1);
            MFMA_PAIR(2, a0h, a0v, a1h, a1v)
            __builtin_amdgcn_s_setprio(0);
            __builtin_amdgcn_s_barrier();
        }
        // ================= phase 2: A i=4,5 ================================
        {
            const s16x8 a0h = *(const s16x8*)(pAh + aoff + 4 * 1024);
            const s16x8 a0v = *(const s16x8*)(pAl + aoff + 4 * 1024);
            const s16x8 a1h = *(const s16x8*)(pAh + aoff + 5 * 1024);
            const s16x8 a1v = *(const s16x8*)(pAl + aoff + 5 * 1024);
            __builtin_amdgcn_sched_barrier(0);
            __builtin_amdgcn_s_barrier();
            asm volatile("s_waitcnt lgkmcnt(0)" ::: "memory");
            __builtin_amdgcn_sched_barrier(0);
            __builtin_amdgcn_s_setprio(1);
            MFMA_PAIR(4, a0h, a0v, a1h, a1v)
            __builtin_amdgcn_s_setprio(0);
            __builtin_amdgcn_s_barrier();
        }
        // ====== phase 3: A i=6,7; drain OLD loads (issued ph0/ph1) =========
        {
            const s16x8 a0h = *(const s16x8*)(pAh + aoff + 6 * 1024);
            const s16x8 a0v = *(const s16x8*)(pAl + aoff + 6 * 1024);
            const s16x8 a1h = *(const s16x8*)(pAh + aoff + 7 * 1024);
            const s16x8 a1v = *(const s16x8*)(pAl + aoff + 7 * 1024);
            __builtin_amdgcn_sched_barrier(0);
            __builtin_amdgcn_s_barrier();
            asm volatile("s_waitcnt lgkmcnt(0)" ::: "memory");
            __builtin_amdgcn_sched_barrier(0);
            __builtin_amdgcn_s_setprio(1);
            MFMA_PAIR(6, a0h, a0v, a1h, a1v)
            __builtin_amdgcn_s_setprio(0);
            asm volatile("s_waitcnt vmcnt(0)" ::: "memory");   // loads are 2-3 phases old
            __builtin_amdgcn_s_barrier();
        }
    }
#undef MFMA_PAIR

    // fold: np-order d = fl(fl(x2-2g)+e2), top-2 over j, 16-lane merge, LDS merge
    float* mb1 = (float*)&lb[0][0][0];   // [4][256]
    float* mb2 = mb1 + 1024;
    int*   mi  = (int*)(mb1 + 2048);

    float e2v[4];
    #pragma unroll
    for (int j = 0; j < 4; ++j)
        e2v[j] = e2[c0 + wn * 64 + j * 16 + (l & 15)];

    #pragma unroll
    for (int i = 0; i < 8; ++i) {
        const float4 x2v = *reinterpret_cast<const float4*>(
            x2 + row0 + wm * 128 + i * 16 + (l >> 4) * 4);
        const float x2a[4] = {x2v.x, x2v.y, x2v.z, x2v.w};
        #pragma unroll
        for (int r = 0; r < 4; ++r) {
            float b1 = 3.4e38f, b2 = 3.4e38f; int ix = 0;
            #pragma unroll
            for (int j = 0; j < 4; ++j) {
                const float d = __fadd_rn(__fmaf_rn(-2.f, acc[i][j][r], x2a[r]), e2v[j]);
                const int cj = c0 + wn * 64 + j * 16 + (l & 15);
                if (d < b1)      { b2 = b1; b1 = d; ix = cj; }
                else if (d < b2) { b2 = d; }
            }
            #pragma unroll
            for (int mm = 1; mm <= 8; mm <<= 1) {
                const float ob1 = __shfl_xor(b1, mm);
                const float ob2 = __shfl_xor(b2, mm);
                const int   oix = __shfl_xor(ix, mm);
                top2_merge(b1, ix, b2, ob1, oix, ob2);
            }
            if ((l & 15) == 0) {
                const int rl = wm * 128 + i * 16 + (l >> 4) * 4 + r;
                mb1[wn * 256 + rl] = b1;
                mb2[wn * 256 + rl] = b2;
                mi [wn * 256 + rl] = ix;
            }
        }
    }
    __syncthreads();
    if (tid < 256) {
        float b1 = mb1[tid], b2 = mb2[tid]; int ix = mi[tid];
        #pragma unroll
        for (int q = 1; q < 4; ++q)
            top2_merge(b1, ix, b2, mb1[q * 256 + tid], mi[q * 256 + tid], mb2[q * 256 + tid]);
        const size_t o = (size_t)ct * M_ROWS + row0 + tid;
        pb1[o] = b1; pb2[o] = b2; pidx[o] = ix;
    }
}

// merge the 32 code-split partials per row; emit idx + ambiguity flags
__global__ __launch_bounds__(256) void combine_kernel(
    const float* __restrict__ pb1, const float* __restrict__ pb2,
    const int* __restrict__ pidx,
    int* __restrict__ idx_i, float* __restrict__ idx_f,
    int* __restrict__ flag_count, int* __restrict__ flag_rows)
{
    const int r = blockIdx.x * 256 + threadIdx.x;
    if (r >= M_ROWS) return;
    float b1 = pb1[r], b2 = pb2[r]; int ix = pidx[r];
    #pragma unroll 4
    for (int ct = 1; ct < 32; ++ct)
        top2_merge(b1, ix, b2, pb1[(size_t)ct * M_ROWS + r],
                   pidx[(size_t)ct * M_ROWS + r], pb2[(size_t)ct * M_ROWS + r]);
    idx_i[r] = ix;
    idx_f[r] = (float)ix;
    if (b2 - b1 < TAU) {
        const int p = atomicAdd(flag_count, 1);
        if (p < MAXFLAG) flag_rows[p] = r;
    }
}

// ---------------------------------------------------------------------------
// FALLBACK (round-3 fp32 path) — only if ws_size too small
// ---------------------------------------------------------------------------
#define BM 64
#define BN 128
#define BH 32
#define PADZ 4
#define PADE 4

__device__ __forceinline__ void stage_transposed(const float* __restrict__ src,
                                                 int row0, int h0,
                                                 float* lds, int R, int ldp) {
    const int nf4 = R * (BH / 4);
    for (int f = threadIdx.x; f < nf4; f += 256) {
        const int r  = f / (BH / 4);
        const int c4 = (f % (BH / 4)) * 4;
        const float4 v = *reinterpret_cast<const float4*>(
            src + (size_t)(row0 + r) * H_DIM + h0 + c4);
        lds[(c4 + 0) * ldp + r] = v.x;
        lds[(c4 + 1) * ldp + r] = v.y;
        lds[(c4 + 2) * ldp + r] = v.z;
        lds[(c4 + 3) * ldp + r] = v.w;
    }
}

__global__ __launch_bounds__(256) void dist_argmin_kernel(
    const float* __restrict__ z, const float* __restrict__ emb,
    const float* __restrict__ x2, const float* __restrict__ e2,
    int* __restrict__ idx_i, float* __restrict__ idx_f,
    int* __restrict__ flag_count, int* __restrict__ flag_rows)
{
    __shared__ float zs[BH * (BM + PADZ)];
    __shared__ float es[BH * (BN + PADE)];
    __shared__ float bd[BM][17];
    __shared__ float bd2[BM][17];
    __shared__ int   bi[BM][17];

    const int row0 = blockIdx.x * BM;
    const int tx = threadIdx.x & 15;
    const int ty = threadIdx.x >> 4;

    float x2r[4];
    #pragma unroll
    for (int i = 0; i < 4; ++i) x2r[i] = x2[row0 + ty * 4 + i];

    float best[4], best2[4];
    int   bidx[4];
    #pragma unroll
    for (int i = 0; i < 4; ++i) { best[i] = 3.4e38f; best2[i] = 3.4e38f; bidx[i] = 0; }

    for (int nt = 0; nt < K_CODES / BN; ++nt) {
        float acc[4][8];
        #pragma unroll
        for (int i = 0; i < 4; ++i)
            #pragma unroll
            for (int j = 0; j < 8; ++j) acc[i][j] = 0.f;

        for (int hc = 0; hc < H_DIM / BH; ++hc) {
            __syncthreads();
            stage_transposed(z,   row0,    hc * BH, zs, BM, BM + PADZ);
            stage_transposed(emb, nt * BN, hc * BH, es, BN, BN + PADE);
            __syncthreads();
            #pragma unroll
            for (int h = 0; h < BH; ++h) {
                const float4 zr = *reinterpret_cast<const float4*>(&zs[h * (BM + PADZ) + ty * 4]);
                const float4 e0 = *reinterpret_cast<const float4*>(&es[h * (BN + PADE) + tx * 4]);
                const float4 e1 = *reinterpret_cast<const float4*>(&es[h * (BN + PADE) + 64 + tx * 4]);
                const float zrv[4] = {zr.x, zr.y, zr.z, zr.w};
                const float ev[8]  = {e0.x, e0.y, e0.z, e0.w, e1.x, e1.y, e1.z, e1.w};
                #pragma unroll
                for (int i = 0; i < 4; ++i)
                    #pragma unroll
                    for (int j = 0; j < 8; ++j)
                        acc[i][j] = fmaf(zrv[i], ev[j], acc[i][j]);
            }
        }
        #pragma unroll
        for (int j = 0; j < 8; ++j) {
            const int code = nt * BN + (j < 4 ? tx * 4 + j : 64 + tx * 4 + (j - 4));
            const float e2v = e2[code];
            #pragma unroll
            for (int i = 0; i < 4; ++i) {
                const float d = __fadd_rn(__fmaf_rn(-2.f, acc[i][j], x2r[i]), e2v);
                if (d < best[i])       { best2[i] = best[i]; best[i] = d; bidx[i] = code; }
                else if (d < best2[i]) { best2[i] = d; }
            }
        }
    }

    __syncthreads();
    #pragma unroll
    for (int i = 0; i < 4; ++i) {
        bd [ty * 4 + i][tx] = best[i];
        bd2[ty * 4 + i][tx] = best2[i];
        bi [ty * 4 + i][tx] = bidx[i];
    }
    __syncthreads();
    if (threadIdx.x < BM) {
        const int r = threadIdx.x;
        float g1 = bd[r][0]; int gi = bi[r][0]; float g2 = bd2[r][0];
        #pragma unroll
        for (int t = 1; t < 16; ++t) {
            const float v = bd[r][t]; const int x = bi[r][t];
            if (v < g1)       { g2 = g1; g1 = v; gi = x; }
            else if (v == g1) { g2 = g1; if (x < gi) gi = x; }
            else              { g2 = fminf(g2, v); }
            g2 = fminf(g2, bd2[r][t]);
        }
        idx_i[row0 + r] = gi;
        idx_f[row0 + r] = (float)gi;
        if (g2 - g1 < TAU) {
            const int p = atomicAdd(flag_count, 1);
            if (p < MAXFLAG) flag_rows[p] = row0 + r;
        }
    }
}

// ---------------------------------------------------------------------------
// fixup stage 1: per (flagged row, code-quarter) block — fp64 ideal-g rescore
// ---------------------------------------------------------------------------
__global__ __launch_bounds__(256) void fixup_scan_kernel(
    const float* __restrict__ z, const float* __restrict__ emb,
    const float* __restrict__ x2, const float* __restrict__ e2,
    const int* __restrict__ flag_count, const int* __restrict__ flag_rows,
    float* __restrict__ qb1, int* __restrict__ qix)
{
    __shared__ float zrow[H_DIM];
    __shared__ float sd[256];
    __shared__ int   si[256];
    int n = *flag_count; if (n > MAXFLAG) n = MAXFLAG;
    const int q = blockIdx.x & 3;
    for (int j = blockIdx.x >> 2; j < n; j += (gridDim.x >> 2)) {
        const int row = flag_rows[j];
        __syncthreads();
        for (int h = threadIdx.x; h < H_DIM; h += 256)
            zrow[h] = z[(size_t)row * H_DIM + h];
        __syncthreads();
        const float x2r = x2[row];
        float bdv = 3.4e38f; int biv = 0x7fffffff;
        for (int k = q * 2048 + threadIdx.x; k < q * 2048 + 2048; k += 256) {
            const float* ek = emb + (size_t)k * H_DIM;
            double d0 = 0.0, d1 = 0.0, d2 = 0.0, d3 = 0.0;
            for (int h = 0; h < H_DIM; h += 4) {
                const float4 ev = *reinterpret_cast<const float4*>(ek + h);
                const float4 zv = *reinterpret_cast<const float4*>(&zrow[h]);
                d0 = fma((double)zv.x, (double)ev.x, d0);
                d1 = fma((double)zv.y, (double)ev.y, d1);
                d2 = fma((double)zv.z, (double)ev.z, d2);
                d3 = fma((double)zv.w, (double)ev.w, d3);
            }
            const float gf = (float)((d0 + d1) + (d2 + d3));
            const float d = __fadd_rn(__fmaf_rn(-2.f, gf, x2r), e2[k]);
            if (d < bdv) { bdv = d; biv = k; }
        }
        sd[threadIdx.x] = bdv; si[threadIdx.x] = biv;
        __syncthreads();
        for (int s = 128; s; s >>= 1) {
            if (threadIdx.x < s) {
                const float od = sd[threadIdx.x + s]; const int oi = si[threadIdx.x + s];
                if (od < sd[threadIdx.x] ||
                    (od == sd[threadIdx.x] && oi < si[threadIdx.x])) {
                    sd[threadIdx.x] = od; si[threadIdx.x] = oi;
                }
            }
            __syncthreads();
        }
        if (threadIdx.x == 0) { qb1[j * 4 + q] = sd[0]; qix[j * 4 + q] = si[0]; }
        __syncthreads();
    }
}

__global__ __launch_bounds__(256) void fixup_merge_kernel(
    const int* __restrict__ flag_count, const int* __restrict__ flag_rows,
    const float* __restrict__ qb1, const int* __restrict__ qix,
    int* __restrict__ idx_i, float* __restrict__ idx_f)
{
    int n = *flag_count; if (n > MAXFLAG) n = MAXFLAG;
    const int t = blockIdx.x * 256 + threadIdx.x;
    if (t >= n) return;
    float b = qb1[t * 4]; int ix = qix[t * 4];
    #pragma unroll
    for (int q = 1; q < 4; ++q) {
        const float ob = qb1[t * 4 + q];
        if (ob < b) { b = ob; ix = qix[t * 4 + q]; }
    }
    idx_i[flag_rows[t]] = ix;
    idx_f[flag_rows[t]] = (float)ix;
}

// ---------------------------------------------------------------------------
// z_st = z + (z_q - z) + both losses; float4 vectorized
// ---------------------------------------------------------------------------
__global__ __launch_bounds__(256) void epilogue_kernel(
    const float* __restrict__ z, const float* __restrict__ emb,
    const int* __restrict__ idx_i,
    float* __restrict__ z_st, float* __restrict__ loss_slots)
{
    const int NQ = M_ROWS * (H_DIM / 4);
    const float4* z4 = reinterpret_cast<const float4*>(z);
    const float4* e4 = reinterpret_cast<const float4*>(emb);
    float4* o4 = reinterpret_cast<float4*>(z_st);
    float local = 0.f;
    for (int q = blockIdx.x * 256 + threadIdx.x; q < NQ; q += gridDim.x * 256) {
        const int r  = q >> 7;
        const int h4 = q & 127;
        const float4 zq = e4[(size_t)idx_i[r] * 128 + h4];
        const float4 zv = z4[q];
        float4 t, o;
        t.x = zq.x - zv.x; o.x = zv.x + t.x;
        t.y = zq.y - zv.y; o.y = zv.y + t.y;
        t.z = zq.z - zv.z; o.z = zv.z + t.z;
        t.w = zq.w - zv.w; o.w = zv.w + t.w;
        o4[q] = o;
        local = fmaf(t.x, t.x, local);
        local = fmaf(t.y, t.y, local);
        local = fmaf(t.z, t.z, local);
        local = fmaf(t.w, t.w, local);
    }
    #pragma unroll
    for (int off = 32; off; off >>= 1) local += __shfl_down(local, off);
    __shared__ float part[4];
    const int lane = threadIdx.x & 63, wid = threadIdx.x >> 6;
    if (lane == 0) part[wid] = local;
    __syncthreads();
    if (threadIdx.x == 0) {
        const float s = (part[0] + part[1] + part[2] + part[3])
                        * (1.f / (float)((size_t)M_ROWS * H_DIM));
        atomicAdd(&loss_slots[0], s);
        atomicAdd(&loss_slots[1], s);
    }
}

// ---------------------------------------------------------------------------
extern "C" void kernel_launch(void* const* d_in, const int* in_sizes, int n_in,
                              void* d_out, int out_size, void* d_ws, size_t ws_size,
                              hipStream_t stream) {
    const float* z   = (const float*)d_in[0];
    const float* emb = (const float*)d_in[1];

    float* out   = (float*)d_out;
    float* z_st  = out;
    float* idx_f = out + (size_t)M_ROWS * H_DIM;
    float* loss  = out + (size_t)M_ROWS * H_DIM + M_ROWS;

    // scratch living temporarily in the z_st output region (dead until epilogue)
    float* pb1  = z_st;
    float* pb2  = z_st + (size_t)32 * M_ROWS;
    int*   pidx = (int*)(z_st + (size_t)64 * M_ROWS);
    float* qb1  = z_st + (size_t)96 * M_ROWS;
    int*   qix  = (int*)(z_st + (size_t)96 * M_ROWS + 4 * MAXFLAG);

    char* ws = (char*)d_ws;
    float* e2     = (float*)(ws + 0);
    float* x2     = (float*)(ws + 32768);
    int*   idx_i  = (int*)  (ws + 163840);
    int*   fcount = (int*)  (ws + 294912);
    int*   frows  = (int*)  (ws + 294976);
    unsigned short* zh = (unsigned short*)(ws + 426048);
    unsigned short* zl = (unsigned short*)(ws + 426048 + 33554432ull);
    unsigned short* eh = (unsigned short*)(ws + 426048 + 67108864ull);
    unsigned short* el = (unsigned short*)(ws + 426048 + 75497472ull);
    const size_t REQ = 426048ull + 83886080ull;   // ~80.4 MB

    const int use_mfma = (ws_size >= REQ) ? 1 : 0;

    hipLaunchKernelGGL(prep_kernel, dim3((M_ROWS + K_CODES) / 8), dim3(256), 0, stream,
                       z, emb, zh, zl, eh, el, x2, e2, loss, fcount, use_mfma);

    if (use_mfma) {
        hipLaunchKernelGGL(mfma_dist_kernel, dim3(4096), dim3(512), 0, stream,
                           zh, zl, eh, el, x2, e2, pb1, pb2, pidx);
        hipLaunchKernelGGL(combine_kernel, dim3(M_ROWS / 256), dim3(256), 0, stream,
                           pb1, pb2, pidx, idx_i, idx_f, fcount, frows);
    } else {
        hipLaunchKernelGGL(dist_argmin_kernel, dim3(M_ROWS / BM), dim3(256), 0, stream,
                           z, emb, x2, e2, idx_i, idx_f, fcount, frows);
    }

    hipLaunchKernelGGL(fixup_scan_kernel, dim3(8192), dim3(256), 0, stream,
                       z, emb, x2, e2, fcount, frows, qb1, qix);
    hipLaunchKernelGGL(fixup_merge_kernel, dim3(MAXFLAG / 256), dim3(256), 0, stream,
                       fcount, frows, qb1, qix, idx_i, idx_f);
    hipLaunchKernelGGL(epilogue_kernel, dim3(2048), dim3(256), 0, stream,
                       z, emb, idx_i, z_st, loss);
}